// Round 9
// baseline (159.926 us; speedup 1.0000x reference)
//
#include <hip/hip_runtime.h>
#include <stdint.h>

#define HEADS 4
#define DHEAD 32
#define NTOK  4096
#define CDIM  256
#define HID   128
#define NBATCH 4

typedef __bf16 bf16x8 __attribute__((ext_vector_type(8)));
typedef __bf16 bf16x4 __attribute__((ext_vector_type(4)));
typedef float  f32x4  __attribute__((ext_vector_type(4)));

// softmax scale folded with log2(e) into Q so scores are in base-2 domain
#define QSCALE (0.17677669529663689f * 1.4426950408889634f)

#define MFMA __builtin_amdgcn_mfma_f32_16x16x32_bf16

// async global->LDS DMA, 16B per lane; LDS dest = uniform base + lane*16
#define ASYNC16(gp, lp)                                                        \
    __builtin_amdgcn_global_load_lds(                                          \
        (const __attribute__((address_space(1))) unsigned int*)(gp),           \
        (__attribute__((address_space(3))) unsigned int*)(lp), 16, 0, 0)

// ---------------------------------------------------------------------------
// qkv_fused r9: occupancy-focused re-grid.  r8 ran 1 block/CU (2 waves/SIMD)
// -- latency-starved.  Now: 256 thr, grid (128 pt x 2 oh x 4 b) = 1024 blocks
// = 4 blocks/CU, 4 waves/SIMD.  Tile 32 p x 256 c (16 KB).  Direct transposed
// gather of x (f32x4 along p, 8 segments of 128 B per instr), in-register
// cvt, swizzled LDS write (slot s of row p holds chunk s^(p&7)).  A-frags
// loaded per-of inside the loop (af[8] = 32 VGPR live, not 96) -> no spill
// at launch_bounds(256,4).  Each wave covers o-frags oh*192 + of*64 + w*16.
// ---------------------------------------------------------------------------
__global__ __launch_bounds__(256, 4) void qkv_fused(
    const float* __restrict__ x, const float* __restrict__ wq,
    __bf16* __restrict__ Q, __bf16* __restrict__ K, __bf16* __restrict__ Vt)
{
    __shared__ __bf16 Xs[32 * 256];      // 16 KB, swizzled

    const int t  = threadIdx.x;
    const int k  = blockIdx.x;           // 1024
    const int b  = k & 3;
    const int oh = (k >> 2) & 1;         // output half: 192 o each
    const int pt = k >> 3;               // 0..127, 32 p each
    const int p0 = pt * 32;
    const int l = t & 63, lm = l & 15, q4 = l >> 4;
    const int w = __builtin_amdgcn_readfirstlane(t >> 6);   // 0..3

    // transposed gather: thread (p4 = (t&7)*4, cw = t>>3) reads 8 f32x4
    // along p for c = cw*8 + u8, i.e. chunk cw of rows p4..p4+3.
    {
        const int p4 = (t & 7) * 4;
        const int cw = t >> 3;           // 0..31
        f32x4 xr[8];
#pragma unroll
        for (int u8 = 0; u8 < 8; ++u8)
            xr[u8] = *(const f32x4*)(
                x + ((size_t)(b * CDIM + cw * 8 + u8)) * NTOK + p0 + p4);
#pragma unroll
        for (int i = 0; i < 4; ++i) {
            const int p = p4 + i;
            bf16x8 v8;
#pragma unroll
            for (int u8 = 0; u8 < 8; ++u8) v8[u8] = (__bf16)xr[u8][i];
            *(bf16x8*)((char*)Xs + p * 512 + ((cw ^ (p & 7)) * 16)) = v8;
        }
    }
    __syncthreads();

#pragma unroll
    for (int of = 0; of < 3; ++of) {
        const int o_base = oh * 192 + of * 64 + w * 16;
        bf16x8 af[8];
#pragma unroll
        for (int kt = 0; kt < 8; ++kt) {
            const float* wr = wq + (size_t)(o_base + lm) * CDIM + kt * 32 + q4 * 8;
            f32x4 w0 = *(const f32x4*)wr;
            f32x4 w1 = *(const f32x4*)(wr + 4);
#pragma unroll
            for (int u = 0; u < 4; ++u) {
                af[kt][u]     = (__bf16)w0[u];
                af[kt][u + 4] = (__bf16)w1[u];
            }
        }

        f32x4 acc[2] = {};
#pragma unroll
        for (int kt = 0; kt < 8; ++kt) {
#pragma unroll
            for (int nf = 0; nf < 2; ++nf) {
                const int p = nf * 16 + lm;
                bf16x8 bfv = *(const bf16x8*)(
                    (const char*)Xs + p * 512 + (((kt * 4 + q4) ^ (lm & 7)) * 16));
                acc[nf] = MFMA(af[kt], bfv, acc[nf], 0, 0, 0);
            }
        }

        const int og0  = o_base + q4 * 4;    // r=0..3 stay in one head
        const int which = og0 >> 7;          // uniform per (oh, of, w)
        const int head  = (og0 >> 5) & 3;
        const int d0    = og0 & 31;
        const int bh    = b * HEADS + head;
#pragma unroll
        for (int nf = 0; nf < 2; ++nf) {
            const int p_g = p0 + nf * 16 + lm;
            f32x4 a = acc[nf];
            if (which == 0) {
                bf16x4 pk = { (__bf16)(a[0] * QSCALE), (__bf16)(a[1] * QSCALE),
                              (__bf16)(a[2] * QSCALE), (__bf16)(a[3] * QSCALE) };
                *(bf16x4*)(Q + ((size_t)bh * NTOK + p_g) * DHEAD + d0) = pk;
            } else if (which == 1) {
                bf16x4 pk = { (__bf16)a[0], (__bf16)a[1], (__bf16)a[2], (__bf16)a[3] };
                *(bf16x4*)(K + ((size_t)bh * NTOK + p_g) * DHEAD + d0) = pk;
            } else {
#pragma unroll
                for (int r = 0; r < 4; ++r)
                    Vt[((size_t)(bh * DHEAD + d0 + r)) * NTOK + p_g] = (__bf16)a[r];
            }
        }
    }
}

// ---------------------------------------------------------------------------
// attn: r6 config unchanged (best measured: 56.2 us).  LDS-staged,
// double-buffered flash attention, split-j x4, 2 row-groups/wave, 128-row
// blocks, grid 2048, launch_bounds(256,5), LDS 24 KB.
// ---------------------------------------------------------------------------
__global__ __launch_bounds__(256, 5) void attn(
    const __bf16* __restrict__ Q, const __bf16* __restrict__ K,
    const __bf16* __restrict__ Vt, __bf16* __restrict__ Opart,
    float* __restrict__ Lsum)
{
    __shared__ uint4  KbufU[2][256];               // [buf][64 rows x 64 B]
    __shared__ uint4  VbufU[2][256];               // [buf][32 rows x 128 B]
    __shared__ __bf16 Ps[4][16][64];               // per-wave, single buffer

    const int t   = threadIdx.x;
    const int blk = blockIdx.x;                    // 2048
    const int bh  = blk & 15;
    const int rest = blk >> 4;                     // 0..127
    const int qt   = rest & 31;                    // 32 tiles of 128 rows
    const int sp   = rest >> 5;                    // j-split 0..3
    const int l = t & 63, lm = l & 15, q4 = l >> 4;
    const int wu = __builtin_amdgcn_readfirstlane(t >> 6);
    const int row0 = qt * 128 + wu * 32;

    const int jt0 = sp * 16, jt1 = jt0 + 16;
    const int psw = (lm & 7) << 4;                 // Ps byte swizzle

    bf16x8 qf[2];
#pragma unroll
    for (int g = 0; g < 2; ++g)
        qf[g] = *(const bf16x8*)(Q + ((size_t)bh * NTOK + row0 + g * 16 + lm) * DHEAD + q4 * 8);

    const char* KbT = (const char*)(K  + (size_t)bh * NTOK * DHEAD);
    const char* VbT = (const char*)(Vt + (size_t)bh * DHEAD * NTOK);

    const int sK_r  = wu * 16 + (l >> 2);
    const int sK_gc = (l & 3) ^ ((sK_r >> 1) & 3);
    const int sV_r  = wu * 8 + (l >> 3);
    const int sV_gc = (l & 7) ^ (sV_r & 7);

    bf16x8 ones;
#pragma unroll
    for (int u = 0; u < 8; ++u) ones[u] = (__bf16)1.0f;

    f32x4 o[2][3] = {};

    {
        const int j00 = jt0 * 64;
        const char* gk = KbT + (size_t)(j00 + sK_r) * 64 + sK_gc * 16;
        ASYNC16(gk, (char*)&KbufU[0][0] + wu * 1024);
        const char* gv = VbT + (size_t)sV_r * (NTOK * 2) + (size_t)j00 * 2 + sV_gc * 16;
        ASYNC16(gv, (char*)&VbufU[0][0] + wu * 1024);
    }
    __syncthreads();

    for (int jt = jt0; jt < jt1; ++jt) {
        const int buf = (jt - jt0) & 1;
        if (jt + 1 < jt1) {
            const int j0n = (jt + 1) * 64;
            const char* gk = KbT + (size_t)(j0n + sK_r) * 64 + sK_gc * 16;
            ASYNC16(gk, (char*)&KbufU[buf ^ 1][0] + wu * 1024);
            const char* gv = VbT + (size_t)sV_r * (NTOK * 2) + (size_t)j0n * 2 + sV_gc * 16;
            ASYNC16(gv, (char*)&VbufU[buf ^ 1][0] + wu * 1024);
        }

        const __bf16* Kl = (const __bf16*)&KbufU[buf][0];
        const __bf16* Vl = (const __bf16*)&VbufU[buf][0];

        bf16x8 kf[4];
#pragma unroll
        for (int j4 = 0; j4 < 4; ++j4) {
            int jl = j4 * 16 + lm;
            int cs = q4 ^ ((jl >> 1) & 3);
            kf[j4] = *(const bf16x8*)(Kl + jl * 32 + cs * 8);
        }
        const int swv = lm & 7;
        bf16x8 vf[4];
        vf[0] = *(const bf16x8*)(Vl + lm * 64        + ((q4    ) ^ swv) * 8);
        vf[1] = *(const bf16x8*)(Vl + (16 + lm) * 64 + ((q4    ) ^ swv) * 8);
        vf[2] = *(const bf16x8*)(Vl + lm * 64        + ((4 + q4) ^ swv) * 8);
        vf[3] = *(const bf16x8*)(Vl + (16 + lm) * 64 + ((4 + q4) ^ swv) * 8);

#pragma unroll
        for (int g = 0; g < 2; ++g) {
            char* psb = (char*)&Ps[wu][0][0] + lm * 128;

            f32x4 st[4];
#pragma unroll
            for (int j4 = 0; j4 < 4; ++j4) {
                f32x4 z = {};
                st[j4] = MFMA(kf[j4], qf[g], z, 0, 0, 0);
            }
#pragma unroll
            for (int j4 = 0; j4 < 4; ++j4) {
                bf16x4 pk;
                pk[0] = (__bf16)__builtin_amdgcn_exp2f(st[j4][0]);
                pk[1] = (__bf16)__builtin_amdgcn_exp2f(st[j4][1]);
                pk[2] = (__bf16)__builtin_amdgcn_exp2f(st[j4][2]);
                pk[3] = (__bf16)__builtin_amdgcn_exp2f(st[j4][3]);
                *(bf16x4*)(psb + ((j4 * 32 + q4 * 8) ^ psw)) = pk;
            }
#pragma unroll
            for (int jc = 0; jc < 2; ++jc) {
                bf16x8 pf = *(const bf16x8*)(psb + ((jc * 64 + q4 * 16) ^ psw));
                o[g][0] = MFMA(pf, vf[jc * 2 + 0], o[g][0], 0, 0, 0);
                o[g][1] = MFMA(pf, vf[jc * 2 + 1], o[g][1], 0, 0, 0);
                o[g][2] = MFMA(pf, ones,           o[g][2], 0, 0, 0);
            }
        }
        __syncthreads();
    }

    const int b = bh >> 2, h = bh & 3;
    __bf16* Op = Opart + (size_t)sp * NBATCH * NTOK * HID;
#pragma unroll
    for (int g = 0; g < 2; ++g) {
        const int rowg0 = row0 + g * 16;
        if (lm == 0)
            *(f32x4*)(Lsum + ((size_t)sp * 16 + bh) * NTOK + rowg0 + q4 * 4) = o[g][2];
#pragma unroll
        for (int r = 0; r < 4; ++r) {
            size_t rowg = (size_t)b * NTOK + rowg0 + q4 * 4 + r;
            Op[rowg * HID + h * DHEAD + lm]      = (__bf16)o[g][0][r];
            Op[rowg * HID + h * DHEAD + 16 + lm] = (__bf16)o[g][1][r];
        }
    }
}

// ---------------------------------------------------------------------------
// out_gemm r9 (combine fused): occupancy-focused re-grid.  r8 ran 2 blocks/CU
// (2 waves/SIMD).  Now: 2048 blocks (32 p x 64 o x b units), Bs 8 KB,
// launch_bounds(256,6) -> 6+ blocks/CU, 6 waves/SIMD.  Same staged-combine
// algebra (stored slot s of row p = chunk s^(p&7); reader (kt*4+q4)^(lm&7)).
// out[b,o,p] = bias[o] + sum_c Wo[o,c] * (sum_sp Opart)/(sum_sp Lsum)
// ---------------------------------------------------------------------------
__global__ __launch_bounds__(256, 6) void out_gemm(
    const float* __restrict__ wo, const __bf16* __restrict__ Opart,
    const float* __restrict__ Lsum, const float* __restrict__ bias,
    float* __restrict__ out)
{
    __shared__ __bf16 Bs[32 * 128];      // 8 KB, swizzled

    const int t  = threadIdx.x;
    const int k  = blockIdx.x;           // 2048
    const int pt = k & 127;              // 32 p each
    const int ot = (k >> 7) & 3;         // 64 o each
    const int b  = k >> 9;               // 0..3
    const int l = t & 63, lm = l & 15, q4 = l >> 4;
    const int w = __builtin_amdgcn_readfirstlane(t >> 6);
    const int p0 = pt * 32;
    const int o0w = ot * 64 + w * 16;
    const size_t per = (size_t)NBATCH * NTOK * HID;

    // staged combine: 8 row-blocks (rb) of 4 p; each lane loads 4 slices of
    // one 16-B chunk, combines, writes linear Bs dest rb*1024 + l*16.
#pragma unroll
    for (int i = 0; i < 2; ++i) {
        const int rb  = i * 4 + w;       // 0..7
        const int p_l = rb * 4 + (l >> 4);
        const int gc  = (l & 15) ^ (p_l & 7);
        const int p   = p0 + p_l;
        const size_t base = ((size_t)(b * NTOK + p)) * HID + gc * 8;
        bf16x8 x0 = *(const bf16x8*)(Opart + base);
        bf16x8 x1 = *(const bf16x8*)(Opart + per + base);
        bf16x8 x2 = *(const bf16x8*)(Opart + 2 * per + base);
        bf16x8 x3 = *(const bf16x8*)(Opart + 3 * per + base);
        const int head = gc >> 2;        // 8 cols stay inside one head
        const size_t li = ((size_t)(b * HEADS + head)) * NTOK + p;
        const float inv = 1.f / (Lsum[li] + Lsum[li + 16 * NTOK] +
                                 Lsum[li + 32 * NTOK] + Lsum[li + 48 * NTOK]);
        bf16x8 o8;
#pragma unroll
        for (int u = 0; u < 8; ++u)
            o8[u] = (__bf16)((((float)x0[u] + (float)x1[u]) +
                              ((float)x2[u] + (float)x3[u])) * inv);
        *(bf16x8*)((char*)Bs + rb * 1024 + l * 16) = o8;
    }

    bf16x8 af[4];
#pragma unroll
    for (int kt = 0; kt < 4; ++kt) {
        const float* wr = wo + (size_t)(o0w + lm) * HID + kt * 32 + q4 * 8;
        f32x4 w0 = *(const f32x4*)wr;
        f32x4 w1 = *(const f32x4*)(wr + 4);
#pragma unroll
        for (int u = 0; u < 4; ++u) {
            af[kt][u]     = (__bf16)w0[u];
            af[kt][u + 4] = (__bf16)w1[u];
        }
    }
    __syncthreads();

    f32x4 acc[2] = {};
#pragma unroll
    for (int kt = 0; kt < 4; ++kt) {
#pragma unroll
        for (int nf = 0; nf < 2; ++nf) {
            const int p = nf * 16 + lm;
            bf16x8 bfv = *(const bf16x8*)(
                (const char*)Bs + p * 256 + (((kt * 4 + q4) ^ (lm & 7)) * 16));
            acc[nf] = MFMA(af[kt], bfv, acc[nf], 0, 0, 0);
        }
    }

    const int og0 = o0w + q4 * 4;
#pragma unroll
    for (int nf = 0; nf < 2; ++nf) {
        const int p_g = p0 + nf * 16 + lm;
#pragma unroll
        for (int r = 0; r < 4; ++r)
            out[((size_t)(b * CDIM + og0 + r)) * NTOK + p_g] =
                acc[nf][r] + bias[og0 + r];
    }
}

// ---------------------------------------------------------------------------
extern "C" void kernel_launch(void* const* d_in, const int* in_sizes, int n_in,
                              void* d_out, int out_size, void* d_ws, size_t ws_size,
                              hipStream_t stream)
{
    const float* x     = (const float*)d_in[0];
    const float* w_qkv = (const float*)d_in[1];
    const float* w_out = (const float*)d_in[2];
    const float* b_out = (const float*)d_in[3];
    float* out = (float*)d_out;

    __bf16* Q  = (__bf16*)d_ws;                           // 4 MB each
    __bf16* K  = Q  + (size_t)16 * NTOK * DHEAD;
    __bf16* Vt = K  + (size_t)16 * NTOK * DHEAD;
    __bf16* Opart = Vt + (size_t)16 * NTOK * DHEAD;       // 4 x 4 MB (bf16)
    float*  Lsum  = (float*)(Opart + (size_t)4 * NBATCH * NTOK * HID); // 4 x 256 KB

    qkv_fused<<<1024, 256, 0, stream>>>(x, w_qkv, Q, K, Vt);
    attn     <<<2048, 256, 0, stream>>>(Q, K, Vt, Opart, Lsum);
    out_gemm <<<2048, 256, 0, stream>>>(w_out, Opart, Lsum, b_out, out);
}

// Round 10
// 145.643 us; speedup vs baseline: 1.0981x; 1.0981x over previous
//
#include <hip/hip_runtime.h>
#include <stdint.h>

#define HEADS 4
#define DHEAD 32
#define NTOK  4096
#define CDIM  256
#define HID   128
#define NBATCH 4

typedef __bf16 bf16x8 __attribute__((ext_vector_type(8)));
typedef __bf16 bf16x4 __attribute__((ext_vector_type(4)));
typedef __bf16 bf16x2 __attribute__((ext_vector_type(2)));
typedef float  f32x4  __attribute__((ext_vector_type(4)));
typedef unsigned int u32x2 __attribute__((ext_vector_type(2)));

// softmax scale folded with log2(e) into Q so scores are in base-2 domain
#define QSCALE (0.17677669529663689f * 1.4426950408889634f)

#define MFMA __builtin_amdgcn_mfma_f32_16x16x32_bf16

// async global->LDS DMA, 16B per lane; LDS dest = uniform base + lane*16
#define ASYNC16(gp, lp)                                                        \
    __builtin_amdgcn_global_load_lds(                                          \
        (const __attribute__((address_space(1))) unsigned int*)(gp),           \
        (__attribute__((address_space(3))) unsigned int*)(lp), 16, 0, 0)

// pack two f32 -> one u32 of 2 bf16 (compiler emits v_cvt_pk_bf16_f32, m240)
__device__ __forceinline__ unsigned pack_bf16(float lo, float hi)
{
    bf16x2 c = { (__bf16)lo, (__bf16)hi };
    return __builtin_bit_cast(unsigned, c);
}

// ---------------------------------------------------------------------------
// qkv_fused (r8 config -- proven): 512 thr, grid (64 pt, 4 b) = 256 blocks.
// Stages the 64p x 256c x tile ONCE; direct transposed f32 gather (64
// consecutive floats per instr), in-register cvt, swizzled LDS write.  Each
// block covers all 384 outputs (wave w owns o-frags w*16 + of*128).
// r9's smaller p-tiles regressed: weight-load amortization dominates, not
// occupancy.
// ---------------------------------------------------------------------------
__global__ __launch_bounds__(512) void qkv_fused(
    const float* __restrict__ x, const float* __restrict__ wq,
    __bf16* __restrict__ Q, __bf16* __restrict__ K, __bf16* __restrict__ Vt)
{
    __shared__ __bf16 Xs[64 * 256];      // 32 KB, swizzled

    const int t  = threadIdx.x;
    const int pt = blockIdx.x;           // 64 (64 p each)
    const int b  = blockIdx.y;           // 4
    const int l = t & 63, lm = l & 15, q4 = l >> 4;
    const int w = __builtin_amdgcn_readfirstlane(t >> 6);   // 0..7
    const int p0 = pt * 64;

    // A fragments from fp32 weights first (independent; overlap the gather)
    bf16x8 af[3][8];
#pragma unroll
    for (int of = 0; of < 3; ++of) {
        const int o_base = w * 16 + of * 128;
#pragma unroll
        for (int kt = 0; kt < 8; ++kt) {
            const float* wr = wq + (size_t)(o_base + lm) * CDIM + kt * 32 + q4 * 8;
            f32x4 w0 = *(const f32x4*)wr;
            f32x4 w1 = *(const f32x4*)(wr + 4);
#pragma unroll
            for (int u = 0; u < 4; ++u) {
                af[of][kt][u]     = (__bf16)w0[u];
                af[of][kt][u + 4] = (__bf16)w1[u];
            }
        }
    }

    // transposed gather + cvt + swizzled LDS write (chunk cc*8+w, row l)
#pragma unroll
    for (int cc = 0; cc < 4; ++cc) {
        float xr[8];
#pragma unroll
        for (int u = 0; u < 8; ++u)
            xr[u] = x[((size_t)(b * CDIM + cc * 64 + w * 8 + u)) * NTOK + p0 + l];
        bf16x8 v8;
#pragma unroll
        for (int u = 0; u < 8; ++u) v8[u] = (__bf16)xr[u];
        *(bf16x8*)((char*)Xs + l * 512 + (((cc * 8 + w) ^ (l & 7)) * 16)) = v8;
    }
    __syncthreads();

    f32x4 acc[3][4] = {};
#pragma unroll
    for (int kt = 0; kt < 8; ++kt) {
#pragma unroll
        for (int nf = 0; nf < 4; ++nf) {
            const int p = nf * 16 + lm;
            bf16x8 bfv = *(const bf16x8*)(
                (const char*)Xs + p * 512 + (((kt * 4 + q4) ^ (lm & 7)) * 16));
#pragma unroll
            for (int of = 0; of < 3; ++of)
                acc[of][nf] = MFMA(af[of][kt], bfv, acc[of][nf], 0, 0, 0);
        }
    }

#pragma unroll
    for (int of = 0; of < 3; ++of) {
        const int og0  = w * 16 + of * 128 + q4 * 4;  // r=0..3 stay in one head
        const int which = og0 >> 7;          // uniform per (w, of)
        const int head  = (og0 >> 5) & 3;
        const int d0    = og0 & 31;
        const int bh    = b * HEADS + head;
#pragma unroll
        for (int nf = 0; nf < 4; ++nf) {
            const int p_g = p0 + nf * 16 + lm;
            f32x4 a = acc[of][nf];
            if (which == 0) {
                bf16x4 pk = { (__bf16)(a[0] * QSCALE), (__bf16)(a[1] * QSCALE),
                              (__bf16)(a[2] * QSCALE), (__bf16)(a[3] * QSCALE) };
                *(bf16x4*)(Q + ((size_t)bh * NTOK + p_g) * DHEAD + d0) = pk;
            } else if (which == 1) {
                bf16x4 pk = { (__bf16)a[0], (__bf16)a[1], (__bf16)a[2], (__bf16)a[3] };
                *(bf16x4*)(K + ((size_t)bh * NTOK + p_g) * DHEAD + d0) = pk;
            } else {
#pragma unroll
                for (int r = 0; r < 4; ++r)
                    Vt[((size_t)(bh * DHEAD + d0 + r)) * NTOK + p_g] = (__bf16)a[r];
            }
        }
    }
}

// ---------------------------------------------------------------------------
// attn: r6 structure (best measured) + VALU-issue trim.  Counters across 6
// configs show the SIMD is ~90% issue-slot-saturated (VALUBusy 46% +
// MfmaUtil 31% + DS/SALU); occupancy/conflicts/traffic all proven
// non-binding.  Trim VALU instructions per score:
//  - v_cvt_pk_bf16_f32 via bf16x2 pairs (replaces elementwise cvt+pack)
//  - single hoisted zero f32x4 for the QK accumulator init
// Everything else byte-identical to r6: split-j x4, 2 row-groups/wave,
// 128-row blocks, grid 2048, launch_bounds(256,5), LDS 24 KB.
// ---------------------------------------------------------------------------
__global__ __launch_bounds__(256, 5) void attn(
    const __bf16* __restrict__ Q, const __bf16* __restrict__ K,
    const __bf16* __restrict__ Vt, __bf16* __restrict__ Opart,
    float* __restrict__ Lsum)
{
    __shared__ uint4  KbufU[2][256];               // [buf][64 rows x 64 B]
    __shared__ uint4  VbufU[2][256];               // [buf][32 rows x 128 B]
    __shared__ __bf16 Ps[4][16][64];               // per-wave, single buffer

    const int t   = threadIdx.x;
    const int blk = blockIdx.x;                    // 2048
    const int bh  = blk & 15;
    const int rest = blk >> 4;                     // 0..127
    const int qt   = rest & 31;                    // 32 tiles of 128 rows
    const int sp   = rest >> 5;                    // j-split 0..3
    const int l = t & 63, lm = l & 15, q4 = l >> 4;
    const int wu = __builtin_amdgcn_readfirstlane(t >> 6);
    const int row0 = qt * 128 + wu * 32;

    const int jt0 = sp * 16, jt1 = jt0 + 16;
    const int psw = (lm & 7) << 4;                 // Ps byte swizzle

    bf16x8 qf[2];
#pragma unroll
    for (int g = 0; g < 2; ++g)
        qf[g] = *(const bf16x8*)(Q + ((size_t)bh * NTOK + row0 + g * 16 + lm) * DHEAD + q4 * 8);

    const char* KbT = (const char*)(K  + (size_t)bh * NTOK * DHEAD);
    const char* VbT = (const char*)(Vt + (size_t)bh * DHEAD * NTOK);

    const int sK_r  = wu * 16 + (l >> 2);
    const int sK_gc = (l & 3) ^ ((sK_r >> 1) & 3);
    const int sV_r  = wu * 8 + (l >> 3);
    const int sV_gc = (l & 7) ^ (sV_r & 7);

    bf16x8 ones;
#pragma unroll
    for (int u = 0; u < 8; ++u) ones[u] = (__bf16)1.0f;

    const f32x4 zf = {};                 // hoisted QK accumulator zero
    f32x4 o[2][3] = {};

    {
        const int j00 = jt0 * 64;
        const char* gk = KbT + (size_t)(j00 + sK_r) * 64 + sK_gc * 16;
        ASYNC16(gk, (char*)&KbufU[0][0] + wu * 1024);
        const char* gv = VbT + (size_t)sV_r * (NTOK * 2) + (size_t)j00 * 2 + sV_gc * 16;
        ASYNC16(gv, (char*)&VbufU[0][0] + wu * 1024);
    }
    __syncthreads();

    for (int jt = jt0; jt < jt1; ++jt) {
        const int buf = (jt - jt0) & 1;
        if (jt + 1 < jt1) {
            const int j0n = (jt + 1) * 64;
            const char* gk = KbT + (size_t)(j0n + sK_r) * 64 + sK_gc * 16;
            ASYNC16(gk, (char*)&KbufU[buf ^ 1][0] + wu * 1024);
            const char* gv = VbT + (size_t)sV_r * (NTOK * 2) + (size_t)j0n * 2 + sV_gc * 16;
            ASYNC16(gv, (char*)&VbufU[buf ^ 1][0] + wu * 1024);
        }

        const __bf16* Kl = (const __bf16*)&KbufU[buf][0];
        const __bf16* Vl = (const __bf16*)&VbufU[buf][0];

        bf16x8 kf[4];
#pragma unroll
        for (int j4 = 0; j4 < 4; ++j4) {
            int jl = j4 * 16 + lm;
            int cs = q4 ^ ((jl >> 1) & 3);
            kf[j4] = *(const bf16x8*)(Kl + jl * 32 + cs * 8);
        }
        const int swv = lm & 7;
        bf16x8 vf[4];
        vf[0] = *(const bf16x8*)(Vl + lm * 64        + ((q4    ) ^ swv) * 8);
        vf[1] = *(const bf16x8*)(Vl + (16 + lm) * 64 + ((q4    ) ^ swv) * 8);
        vf[2] = *(const bf16x8*)(Vl + lm * 64        + ((4 + q4) ^ swv) * 8);
        vf[3] = *(const bf16x8*)(Vl + (16 + lm) * 64 + ((4 + q4) ^ swv) * 8);

#pragma unroll
        for (int g = 0; g < 2; ++g) {
            char* psb = (char*)&Ps[wu][0][0] + lm * 128;

            f32x4 st[4];
#pragma unroll
            for (int j4 = 0; j4 < 4; ++j4)
                st[j4] = MFMA(kf[j4], qf[g], zf, 0, 0, 0);
#pragma unroll
            for (int j4 = 0; j4 < 4; ++j4) {
                float e0 = __builtin_amdgcn_exp2f(st[j4][0]);
                float e1 = __builtin_amdgcn_exp2f(st[j4][1]);
                float e2 = __builtin_amdgcn_exp2f(st[j4][2]);
                float e3 = __builtin_amdgcn_exp2f(st[j4][3]);
                u32x2 pk = { pack_bf16(e0, e1), pack_bf16(e2, e3) };
                *(u32x2*)(psb + ((j4 * 32 + q4 * 8) ^ psw)) = pk;
            }
#pragma unroll
            for (int jc = 0; jc < 2; ++jc) {
                bf16x8 pf = *(const bf16x8*)(psb + ((jc * 64 + q4 * 16) ^ psw));
                o[g][0] = MFMA(pf, vf[jc * 2 + 0], o[g][0], 0, 0, 0);
                o[g][1] = MFMA(pf, vf[jc * 2 + 1], o[g][1], 0, 0, 0);
                o[g][2] = MFMA(pf, ones,           o[g][2], 0, 0, 0);
            }
        }
        __syncthreads();
    }

    const int b = bh >> 2, h = bh & 3;
    __bf16* Op = Opart + (size_t)sp * NBATCH * NTOK * HID;
#pragma unroll
    for (int g = 0; g < 2; ++g) {
        const int rowg0 = row0 + g * 16;
        if (lm == 0)
            *(f32x4*)(Lsum + ((size_t)sp * 16 + bh) * NTOK + rowg0 + q4 * 4) = o[g][2];
#pragma unroll
        for (int r = 0; r < 4; ++r) {
            size_t rowg = (size_t)b * NTOK + rowg0 + q4 * 4 + r;
            Op[rowg * HID + h * DHEAD + lm]      = (__bf16)o[g][0][r];
            Op[rowg * HID + h * DHEAD + 16 + lm] = (__bf16)o[g][1][r];
        }
    }
}

// ---------------------------------------------------------------------------
// out_gemm (r8 config -- proven): combine fused, reg-staged, 512 blocks
// (32 pt x 4 ot x 4 b), Bs 32 KB.  r9's 2048-block regrid regressed (4x
// weight re-reads); reverted.
// out[b,o,p] = bias[o] + sum_c Wo[o,c] * (sum_sp Opart)/(sum_sp Lsum)
// ---------------------------------------------------------------------------
__global__ __launch_bounds__(256) void out_gemm(
    const float* __restrict__ wo, const __bf16* __restrict__ Opart,
    const float* __restrict__ Lsum, const float* __restrict__ bias,
    float* __restrict__ out)
{
    __shared__ __bf16 Bs[128 * 128];     // 32 KB, swizzled

    const int t  = threadIdx.x;
    const int pt = blockIdx.x;           // 32
    const int ot = blockIdx.y;           // 4 (64 o each)
    const int b  = blockIdx.z;           // 4
    const int l = t & 63, lm = l & 15, q4 = l >> 4;
    const int w = __builtin_amdgcn_readfirstlane(t >> 6);
    const int p0 = pt * 128;
    const int o0w = ot * 64 + w * 16;
    const size_t per = (size_t)NBATCH * NTOK * HID;

    // staged combine: same (p_l, gc) gather as the DMA version, same linear
    // Bs destination (i*4+w)*1024 + lane*16.
#pragma unroll
    for (int i = 0; i < 8; ++i) {
        const int p_l = (i * 4 + w) * 4 + (l >> 4);
        const int gc  = (l & 15) ^ (p_l & 7);
        const int p   = p0 + p_l;
        const size_t base = ((size_t)(b * NTOK + p)) * HID + gc * 8;
        bf16x8 x0 = *(const bf16x8*)(Opart + base);
        bf16x8 x1 = *(const bf16x8*)(Opart + per + base);
        bf16x8 x2 = *(const bf16x8*)(Opart + 2 * per + base);
        bf16x8 x3 = *(const bf16x8*)(Opart + 3 * per + base);
        const int head = gc >> 2;        // 8 cols stay inside one head
        const size_t li = ((size_t)(b * HEADS + head)) * NTOK + p;
        const float inv = 1.f / (Lsum[li] + Lsum[li + 16 * NTOK] +
                                 Lsum[li + 32 * NTOK] + Lsum[li + 48 * NTOK]);
        bf16x8 o8;
#pragma unroll
        for (int u = 0; u < 8; ++u)
            o8[u] = (__bf16)((((float)x0[u] + (float)x1[u]) +
                              ((float)x2[u] + (float)x3[u])) * inv);
        *(bf16x8*)((char*)Bs + (i * 4 + w) * 1024 + l * 16) = o8;
    }

    bf16x8 af[4];
#pragma unroll
    for (int kt = 0; kt < 4; ++kt) {
        const float* wr = wo + (size_t)(o0w + lm) * HID + kt * 32 + q4 * 8;
        f32x4 w0 = *(const f32x4*)wr;
        f32x4 w1 = *(const f32x4*)(wr + 4);
#pragma unroll
        for (int u = 0; u < 4; ++u) {
            af[kt][u]     = (__bf16)w0[u];
            af[kt][u + 4] = (__bf16)w1[u];
        }
    }
    __syncthreads();

    f32x4 acc[8] = {};
#pragma unroll
    for (int kt = 0; kt < 4; ++kt) {
#pragma unroll
        for (int nf = 0; nf < 8; ++nf) {
            const int p = nf * 16 + lm;
            bf16x8 bfv = *(const bf16x8*)(
                (const char*)Bs + p * 256 + (((kt * 4 + q4) ^ (lm & 7)) * 16));
            acc[nf] = MFMA(af[kt], bfv, acc[nf], 0, 0, 0);
        }
    }

    const int og0 = o0w + q4 * 4;
#pragma unroll
    for (int nf = 0; nf < 8; ++nf) {
        const int p_g = p0 + nf * 16 + lm;
#pragma unroll
        for (int r = 0; r < 4; ++r)
            out[((size_t)(b * CDIM + og0 + r)) * NTOK + p_g] =
                acc[nf][r] + bias[og0 + r];
    }
}

// ---------------------------------------------------------------------------
extern "C" void kernel_launch(void* const* d_in, const int* in_sizes, int n_in,
                              void* d_out, int out_size, void* d_ws, size_t ws_size,
                              hipStream_t stream)
{
    const float* x     = (const float*)d_in[0];
    const float* w_qkv = (const float*)d_in[1];
    const float* w_out = (const float*)d_in[2];
    const float* b_out = (const float*)d_in[3];
    float* out = (float*)d_out;

    __bf16* Q  = (__bf16*)d_ws;                           // 4 MB each
    __bf16* K  = Q  + (size_t)16 * NTOK * DHEAD;
    __bf16* Vt = K  + (size_t)16 * NTOK * DHEAD;
    __bf16* Opart = Vt + (size_t)16 * NTOK * DHEAD;       // 4 x 4 MB (bf16)
    float*  Lsum  = (float*)(Opart + (size_t)4 * NBATCH * NTOK * HID); // 4 x 256 KB

    qkv_fused<<<dim3(64, NBATCH),   512, 0, stream>>>(x, w_qkv, Q, K, Vt);
    attn     <<<2048, 256, 0, stream>>>(Q, K, Vt, Opart, Lsum);
    out_gemm <<<dim3(32, 4, NBATCH), 256, 0, stream>>>(w_out, Opart, Lsum, b_out, out);
}